// Round 1
// baseline (12227.592 us; speedup 1.0000x reference)
//
#include <hip/hip_runtime.h>
#include <cstdint>
#include <cstddef>

#define TT 512
#define BB 64
#define HH 256
#define NG 1024
#define DI 768
#define KY 32

__device__ __forceinline__ float sigf(float x) {
    return __fdividef(1.f, 1.f + __expf(-x));
}
__device__ __forceinline__ float tanhfast(float x) {
    // tanh(x) = 2*sigmoid(2x) - 1
    return fmaf(2.f, sigf(2.f * x), -1.f);
}

// ---------------------------------------------------------------------------
// Kernel A: G_pre[tl][b][j] = sents[b][t0+tl][:] @ Wih[j][32:800]^T + bih[j]+bhh[j]
// grid (16, Tc), block 256. 64x64 output tile, K=768.
// ---------------------------------------------------------------------------
__global__ __launch_bounds__(256) void kgemm(
    const float* __restrict__ sents, const float* __restrict__ Wih,
    const float* __restrict__ bih, const float* __restrict__ bhh,
    float* __restrict__ gpre, int t0)
{
    __shared__ float As[16][68];   // [k][b], pad 68 keeps float4 alignment + conflict-free
    __shared__ float Bs[16][64];   // [k][j]
    const int tid = threadIdx.x;
    const int tl = blockIdx.y;
    const int jb = blockIdx.x * 64;
    const int tx = tid & 15, ty = tid >> 4;
    const int lr = tid >> 2, kq = tid & 3;

    float acc[4][4];
#pragma unroll
    for (int m = 0; m < 4; ++m)
#pragma unroll
        for (int n = 0; n < 4; ++n) acc[m][n] = 0.f;

    const float* arow = sents + ((size_t)lr * TT + t0 + tl) * DI;  // b = lr
    const float* brow = Wih + (size_t)(jb + lr) * 800 + KY;        // j = jb+lr

    for (int k0 = 0; k0 < DI; k0 += 16) {
        float4 av = *(const float4*)(arow + k0 + kq * 4);
        float4 bv = *(const float4*)(brow + k0 + kq * 4);
        __syncthreads();
        As[kq * 4 + 0][lr] = av.x; As[kq * 4 + 1][lr] = av.y;
        As[kq * 4 + 2][lr] = av.z; As[kq * 4 + 3][lr] = av.w;
        Bs[kq * 4 + 0][lr] = bv.x; Bs[kq * 4 + 1][lr] = bv.y;
        Bs[kq * 4 + 2][lr] = bv.z; Bs[kq * 4 + 3][lr] = bv.w;
        __syncthreads();
#pragma unroll
        for (int k = 0; k < 16; ++k) {
            float4 a4 = *(const float4*)&As[k][ty * 4];
            float4 b4 = *(const float4*)&Bs[k][tx * 4];
            acc[0][0] = fmaf(a4.x, b4.x, acc[0][0]);
            acc[0][1] = fmaf(a4.x, b4.y, acc[0][1]);
            acc[0][2] = fmaf(a4.x, b4.z, acc[0][2]);
            acc[0][3] = fmaf(a4.x, b4.w, acc[0][3]);
            acc[1][0] = fmaf(a4.y, b4.x, acc[1][0]);
            acc[1][1] = fmaf(a4.y, b4.y, acc[1][1]);
            acc[1][2] = fmaf(a4.y, b4.z, acc[1][2]);
            acc[1][3] = fmaf(a4.y, b4.w, acc[1][3]);
            acc[2][0] = fmaf(a4.z, b4.x, acc[2][0]);
            acc[2][1] = fmaf(a4.z, b4.y, acc[2][1]);
            acc[2][2] = fmaf(a4.z, b4.z, acc[2][2]);
            acc[2][3] = fmaf(a4.z, b4.w, acc[2][3]);
            acc[3][0] = fmaf(a4.w, b4.x, acc[3][0]);
            acc[3][1] = fmaf(a4.w, b4.y, acc[3][1]);
            acc[3][2] = fmaf(a4.w, b4.z, acc[3][2]);
            acc[3][3] = fmaf(a4.w, b4.w, acc[3][3]);
        }
    }
    const int j0 = jb + tx * 4;
    float4 bias4;
    bias4.x = bih[j0 + 0] + bhh[j0 + 0];
    bias4.y = bih[j0 + 1] + bhh[j0 + 1];
    bias4.z = bih[j0 + 2] + bhh[j0 + 2];
    bias4.w = bih[j0 + 3] + bhh[j0 + 3];
#pragma unroll
    for (int m = 0; m < 4; ++m) {
        int row = ty * 4 + m;  // = b
        float4 o;
        o.x = acc[m][0] + bias4.x; o.y = acc[m][1] + bias4.y;
        o.z = acc[m][2] + bias4.z; o.w = acc[m][3] + bias4.w;
        *(float4*)(gpre + ((size_t)tl * BB + row) * NG + j0) = o;
    }
}

// ---------------------------------------------------------------------------
// Kernel S: SHi[tl][b][k] = sents[b][t0+tl][:] @ Waff[k][256:1024]^T + baff[k]
// 4 rows per 256-thread block; wave-wide shuffle reduce.
// ---------------------------------------------------------------------------
__global__ __launch_bounds__(256) void kshi(
    const float* __restrict__ sents, const float* __restrict__ Waff,
    const float* __restrict__ baff, float* __restrict__ shi, int t0)
{
    const int tid = threadIdx.x;
    const int lane = tid & 63;
    const int r = blockIdx.x * 4 + (tid >> 6);
    const int b = r & 63, tl = r >> 6;
    const float* hi = sents + ((size_t)b * TT + t0 + tl) * DI;
    float p0 = 0.f, p1 = 0.f;
#pragma unroll
    for (int kk = 0; kk < 12; ++kk) {
        int k = kk * 64 + lane;
        float x = hi[k];
        p0 = fmaf(x, Waff[HH + k], p0);        // Waff[0][256+k]
        p1 = fmaf(x, Waff[NG + HH + k], p1);   // Waff[1][256+k]
    }
#pragma unroll
    for (int off = 32; off >= 1; off >>= 1) {
        p0 += __shfl_xor(p0, off, 64);
        p1 += __shfl_xor(p1, off, 64);
    }
    if (lane == 0) {
        shi[(size_t)r * 2 + 0] = p0 + baff[0];
        shi[(size_t)r * 2 + 1] = p1 + baff[1];
    }
}

// ---------------------------------------------------------------------------
// Kernel R: the sequential LSTM. One WG (1024 thr) per batch element.
// Whh held in registers: thread (wave,lane): j = wave*16+(lane&15) is its
// h-dim, q = lane>>4 is its K-quarter; owns Whh[j+256g][64q:64q+64), g=0..3.
// h broadcast via LDS; K-partials combined by shfl_xor(16),(32) in-wave.
// ---------------------------------------------------------------------------
__global__ __launch_bounds__(1024, 1) void krec(
    const float* __restrict__ gpre,   // [Tc][64][1024]
    const float* __restrict__ shi,    // [Tc][64][2]
    const float* __restrict__ Whh,    // [1024][256]
    const float* __restrict__ mask,   // [64][512]
    float* __restrict__ out,          // [64][512][2]
    float* __restrict__ sh, float* __restrict__ sc, int* __restrict__ sp,
    const float* __restrict__ Wih, const float* __restrict__ tag,
    const float* __restrict__ Waff,
    int t0, int Tc, int first)
{
    const int b = blockIdx.x;
    const int tid = threadIdx.x;
    const int wave = tid >> 6, lane = tid & 63;
    const int jl = lane & 15, q = lane >> 4;
    const int j = wave * 16 + jl;   // h-dim handled by this thread

    __shared__ float hs[HH];
    __shared__ float P[2][NG];
    __shared__ float red[16][2];
    __shared__ int predS;
    __shared__ float tg[2][KY];

    // ---- load Whh slices into registers (256 VGPRs) ----
    float4 w[4][16];
#pragma unroll
    for (int g = 0; g < 4; ++g) {
        const float4* src = (const float4*)(Whh + (size_t)(j + g * HH) * HH + q * 64);
#pragma unroll
        for (int kk = 0; kk < 16; ++kk) w[g][kk] = src[kk];
    }

    // ---- P[r][j] = tag_em[r] @ Wih[j][0:32]^T ----
    if (tid < 2 * KY) tg[tid >> 5][tid & 31] = tag[tid];
    __syncthreads();
    for (int idx = tid; idx < 2 * NG; idx += 1024) {
        int r = idx >> 10, jj = idx & (NG - 1);
        const float4* wr = (const float4*)(Wih + (size_t)jj * 800);
        float s = 0.f;
#pragma unroll
        for (int kk = 0; kk < 8; ++kk) {
            float4 wv = wr[kk];
            s = fmaf(wv.x, tg[r][kk * 4 + 0], s);
            s = fmaf(wv.y, tg[r][kk * 4 + 1], s);
            s = fmaf(wv.z, tg[r][kk * 4 + 2], s);
            s = fmaf(wv.w, tg[r][kk * 4 + 3], s);
        }
        P[r][jj] = s;
    }

    const float waff0 = Waff[j];        // Waff[0][j]  (h part: cols 0..255)
    const float waff1 = Waff[NG + j];   // Waff[1][j]

    // ---- state ----
    float hreg, creg;
    if (first) {
        hreg = 0.f; creg = 0.f;
        if (tid == 0) predS = -1;
    } else {
        hreg = sh[(size_t)b * HH + j];
        creg = sc[(size_t)b * HH + j];
        if (tid == 0) predS = sp[b];
    }
    if (q == 0) hs[j] = hreg;
    __syncthreads();

    for (int tl = 0; tl < Tc; ++tl) {
        const int t = t0 + tl;
        const int pred = predS;

        // ---- matvec: acc[g] = Whh[j+256g][64q:64q+64) . h[64q:64q+64) ----
        float acc0 = 0.f, acc1 = 0.f, acc2 = 0.f, acc3 = 0.f;
        const float4* h4 = ((const float4*)hs) + q * 16;
#pragma unroll
        for (int kk = 0; kk < 16; ++kk) {
            float4 hv = h4[kk];
            acc0 = fmaf(w[0][kk].x, hv.x, acc0); acc0 = fmaf(w[0][kk].y, hv.y, acc0);
            acc0 = fmaf(w[0][kk].z, hv.z, acc0); acc0 = fmaf(w[0][kk].w, hv.w, acc0);
            acc1 = fmaf(w[1][kk].x, hv.x, acc1); acc1 = fmaf(w[1][kk].y, hv.y, acc1);
            acc1 = fmaf(w[1][kk].z, hv.z, acc1); acc1 = fmaf(w[1][kk].w, hv.w, acc1);
            acc2 = fmaf(w[2][kk].x, hv.x, acc2); acc2 = fmaf(w[2][kk].y, hv.y, acc2);
            acc2 = fmaf(w[2][kk].z, hv.z, acc2); acc2 = fmaf(w[2][kk].w, hv.w, acc2);
            acc3 = fmaf(w[3][kk].x, hv.x, acc3); acc3 = fmaf(w[3][kk].y, hv.y, acc3);
            acc3 = fmaf(w[3][kk].z, hv.z, acc3); acc3 = fmaf(w[3][kk].w, hv.w, acc3);
        }
        // combine K-quarters (lanes differing in q bits: xor 16, 32)
        acc0 += __shfl_xor(acc0, 16, 64); acc0 += __shfl_xor(acc0, 32, 64);
        acc1 += __shfl_xor(acc1, 16, 64); acc1 += __shfl_xor(acc1, 32, 64);
        acc2 += __shfl_xor(acc2, 16, 64); acc2 += __shfl_xor(acc2, 32, 64);
        acc3 += __shfl_xor(acc3, 16, 64); acc3 += __shfl_xor(acc3, 32, 64);

        const float* gp = gpre + ((size_t)tl * BB + b) * NG;
        float pv0 = 0.f, pv1 = 0.f, pv2 = 0.f, pv3 = 0.f;
        if (pred >= 0) {
            pv0 = P[pred][j + 0 * HH]; pv1 = P[pred][j + 1 * HH];
            pv2 = P[pred][j + 2 * HH]; pv3 = P[pred][j + 3 * HH];
        }
        float gi = acc0 + gp[j + 0 * HH] + pv0;
        float gf = acc1 + gp[j + 1 * HH] + pv1;
        float gg = acc2 + gp[j + 2 * HH] + pv2;
        float go = acc3 + gp[j + 3 * HH] + pv3;

        float ig = sigf(gi), fg = sigf(gf);
        float g2 = tanhfast(gg), og = sigf(go);
        float cn = fmaf(fg, creg, ig * g2);
        float hn = og * tanhfast(cn);
        float mi = mask[(size_t)b * TT + t];
        float ho = hn * mi + hreg * (1.f - mi);
        float co = cn * mi + creg * (1.f - mi);

        __syncthreads();                 // all waves done reading hs / predS
        if (q == 0) hs[j] = ho;
        hreg = ho; creg = co;

        // ---- score reduce: only q==0 lanes contribute (one copy per j) ----
        float p0 = (q == 0) ? hn * waff0 : 0.f;
        float p1 = (q == 0) ? hn * waff1 : 0.f;
#pragma unroll
        for (int off = 32; off >= 1; off >>= 1) {
            p0 += __shfl_xor(p0, off, 64);
            p1 += __shfl_xor(p1, off, 64);
        }
        if (lane == 0) { red[wave][0] = p0; red[wave][1] = p1; }
        __syncthreads();                 // red + hs visible

        if (tid == 0) {
            float s0 = 0.f, s1 = 0.f;
#pragma unroll
            for (int wv = 0; wv < 16; ++wv) { s0 += red[wv][0]; s1 += red[wv][1]; }
            const float* s2 = shi + ((size_t)tl * BB + b) * 2;
            s0 += s2[0]; s1 += s2[1];
            predS = (s1 > s0) ? 1 : 0;
            float m = fmaxf(s0, s1);
            float lse = m + log1pf(expf(-fabsf(s0 - s1)));
            float* op = out + ((size_t)b * TT + t) * 2;
            op[0] = s0 - lse; op[1] = s1 - lse;
        }
        __syncthreads();                 // predS visible for next step
    }

    if (q == 0) {
        sh[(size_t)b * HH + j] = hreg;
        sc[(size_t)b * HH + j] = creg;
    }
    if (tid == 0) sp[b] = predS;
}

// ---------------------------------------------------------------------------
extern "C" void kernel_launch(void* const* d_in, const int* in_sizes, int n_in,
                              void* d_out, int out_size, void* d_ws, size_t ws_size,
                              hipStream_t stream) {
    (void)in_sizes; (void)n_in; (void)out_size;
    const float* sents = (const float*)d_in[0];
    const float* mask  = (const float*)d_in[1];
    const float* Wih   = (const float*)d_in[2];
    const float* Whh   = (const float*)d_in[3];
    const float* bih   = (const float*)d_in[4];
    const float* bhh   = (const float*)d_in[5];
    const float* Waff  = (const float*)d_in[6];
    const float* baff  = (const float*)d_in[7];
    const float* tag   = (const float*)d_in[8];
    float* out = (float*)d_out;

    // pick largest chunk Tc that fits in workspace
    int Tc = 8;
    const int cands[7] = {512, 256, 128, 64, 32, 16, 8};
    for (int i = 0; i < 7; ++i) {
        size_t need = (size_t)cands[i] * BB * NG * 4   // gpre
                    + (size_t)cands[i] * BB * 2 * 4    // shi
                    + (size_t)BB * HH * 4 * 2          // h,c state
                    + BB * 4 + 1024;                   // pred + slack
        if (need <= ws_size) { Tc = cands[i]; break; }
    }

    char* wsp = (char*)d_ws;
    float* gpre = (float*)wsp; wsp += (size_t)Tc * BB * NG * 4;
    float* shiw = (float*)wsp; wsp += (size_t)Tc * BB * 2 * 4;
    float* shst = (float*)wsp; wsp += (size_t)BB * HH * 4;
    float* scst = (float*)wsp; wsp += (size_t)BB * HH * 4;
    int*   spst = (int*)wsp;

    const int nch = TT / Tc;
    for (int c = 0; c < nch; ++c) {
        const int t0 = c * Tc;
        kgemm<<<dim3(16, Tc), 256, 0, stream>>>(sents, Wih, bih, bhh, gpre, t0);
        kshi<<<dim3(Tc * 16), 256, 0, stream>>>(sents, Waff, baff, shiw, t0);
        krec<<<dim3(BB), 1024, 0, stream>>>(gpre, shiw, Whh, mask, out,
                                            shst, scst, spst,
                                            Wih, tag, Waff, t0, Tc, (c == 0) ? 1 : 0);
    }
}